// Round 5
// baseline (210.457 us; speedup 1.0000x reference)
//
#include <hip/hip_runtime.h>
#include <math.h>

#define TBL 512
#define SBLK 512   // score blocks in k12
#define K4BLK 768  // k4 grid

// workspace layout (float offsets)
#define OFF_MM     64       // 2 floats: smin, smax (written by k3)
#define OFF_CNT    66       // 1 uint: k4 completion counter (zeroed by k12)
#define OFF_C2     128      // 128
#define OFF_EMB    256      // 128
#define OFF_MT     512      // 64*128  (M transposed: Mt[d][j])
#define OFF_WGT    8704     // 32*128 accumulator copies
#define OFF_BMIN   12800    // SBLK per-block minima
#define OFF_BMAX   13312    // SBLK per-block maxima
#define OFF_SCORES 13824    // N (padded); pair table follows at runtime offset

// ---------------- K12: prep (emb, Mt, c2, zeros) + scores + block minmax --
__global__ void __launch_bounds__(256) k12(
        const float* __restrict__ X,  const float* __restrict__ We,
        const float* __restrict__ be, const float* __restrict__ Wv,
        const float* __restrict__ Wq, const float* __restrict__ bq,
        const float* __restrict__ Wk, const float* __restrict__ bk,
        const int* __restrict__ selfp, float* __restrict__ ws,
        int N, int APB)
{
    const int b = blockIdx.x, t = threadIdx.x;
    if (b == 0) {
        // self embedding (for head) + zero accumulators + completion counter
        const int self = *selfp;
        const float4* xs4 = (const float4*)(X + (size_t)self * 64);
        if (t < 128) {
            const float4* wr = (const float4*)(We + t*64);
            float ax = 0.f, ay = 0.f, az = 0.f, aw = 0.f;
            #pragma unroll
            for (int q = 0; q < 16; ++q) {
                const float4 wv = wr[q];
                const float4 xv = xs4[q];     // uniform -> s_load
                ax = __builtin_fmaf(wv.x, xv.x, ax);
                ay = __builtin_fmaf(wv.y, xv.y, ay);
                az = __builtin_fmaf(wv.z, xv.z, az);
                aw = __builtin_fmaf(wv.w, xv.w, aw);
            }
            ws[OFF_EMB + t] = ((ax + ay) + (az + aw)) + be[t];
        }
        for (int i = t; i < 32*128; i += 256) ws[OFF_WGT + i] = 0.f;
        if (t == 0) *(unsigned*)(ws + OFF_CNT) = 0u;
    } else if (b <= 128) {
        const int r = b - 1;   // row r of M = (Wv @ We); store transposed Mt[d][r]
        if (t < 64) {
            float acc = 0.f;
            #pragma unroll 8
            for (int e = 0; e < 128; ++e)
                acc = __builtin_fmaf(Wv[r*128 + e], We[e*64 + t], acc);
            ws[OFF_MT + t*128 + r] = acc;
        } else if (t == 64) {
            float acc = 0.f;
            for (int e = 0; e < 128; ++e)
                acc = __builtin_fmaf(Wv[r*128 + e], be[e], acc);
            ws[OFF_C2 + r] = acc;
        }
    } else {
        // ---- score block: redundantly fold v = We^T Wk^T q / sqrt(E) ----
        __shared__ float emb[128], qv[128], uu[128], vv[64];
        __shared__ float s0s;
        const int self = *selfp;
        const float4* xs4 = (const float4*)(X + (size_t)self * 64);
        if (t < 128) {
            const float4* wr = (const float4*)(We + t*64);
            float ax = 0.f, ay = 0.f, az = 0.f, aw = 0.f;
            #pragma unroll
            for (int q = 0; q < 16; ++q) {
                const float4 wv = wr[q];
                const float4 xv = xs4[q];
                ax = __builtin_fmaf(wv.x, xv.x, ax);
                ay = __builtin_fmaf(wv.y, xv.y, ay);
                az = __builtin_fmaf(wv.z, xv.z, az);
                aw = __builtin_fmaf(wv.w, xv.w, aw);
            }
            emb[t] = ((ax + ay) + (az + aw)) + be[t];
        }
        __syncthreads();
        if (t < 128) {
            const float4* wr = (const float4*)(Wq + t*128);
            float ax = 0.f, ay = 0.f, az = 0.f, aw = 0.f;
            #pragma unroll 8
            for (int q = 0; q < 32; ++q) {
                const float4 wv = wr[q];
                const float4 ev = ((const float4*)emb)[q];
                ax = __builtin_fmaf(wv.x, ev.x, ax);
                ay = __builtin_fmaf(wv.y, ev.y, ay);
                az = __builtin_fmaf(wv.z, ev.z, az);
                aw = __builtin_fmaf(wv.w, ev.w, aw);
            }
            qv[t] = ((ax + ay) + (az + aw)) + bq[t];
        }
        __syncthreads();
        if (t < 128) {
            float acc = 0.f;
            #pragma unroll 8
            for (int e = 0; e < 128; ++e)
                acc = __builtin_fmaf(Wk[e*128 + t], qv[e], acc);   // coalesced
            uu[t] = acc;
        }
        __syncthreads();
        const float rs = 0.08838834764831845f;  // 1/sqrt(128)
        if (t < 64) {
            float acc = 0.f;
            #pragma unroll 8
            for (int e = 0; e < 128; ++e)
                acc = __builtin_fmaf(We[e*64 + t], uu[e], acc);    // coalesced
            vv[t] = acc * rs;
        } else if (t == 64) {
            float acc = 0.f;
            for (int e = 0; e < 128; ++e)
                acc += be[e]*uu[e] + bk[e]*qv[e];
            s0s = acc * rs;
        }
        __syncthreads();

        // ---- scores for this block's agent slice ----
        const int s = b - 129;
        const int base = s * APB;
        const int n1 = min(N, base + APB);
        const int l16 = t & 15;
        const int slot = t >> 4;        // 16 agents per 256-thread pass
        const float4 vch = *(const float4*)(vv + l16*4);
        const float s0 = s0s;
        const float4* X4 = (const float4*)X;
        float* scores = ws + OFF_SCORES;
        float smin = INFINITY, smax = -INFINITY;
        for (int n = base + slot; n < n1; n += 16) {
            const float4 xv = X4[(size_t)n*16 + l16];
            float sc = xv.x*vch.x + xv.y*vch.y + xv.z*vch.z + xv.w*vch.w;
            sc += __shfl_xor(sc, 1);
            sc += __shfl_xor(sc, 2);
            sc += __shfl_xor(sc, 4);
            sc += __shfl_xor(sc, 8);
            sc += s0;
            if (l16 == 0) scores[n] = sc;
            smin = fminf(smin, sc);
            smax = fmaxf(smax, sc);
        }
        #pragma unroll
        for (int m = 32; m >= 1; m >>= 1) {
            smin = fminf(smin, __shfl_xor(smin, m));
            smax = fmaxf(smax, __shfl_xor(smax, m));
        }
        __shared__ float rmn[4], rmx[4];
        const int wv = t >> 6;
        if ((t & 63) == 0) { rmn[wv] = smin; rmx[wv] = smax; }
        __syncthreads();
        if (t == 0) {
            ws[OFF_BMIN + s] = fminf(fminf(rmn[0], rmn[1]), fminf(rmn[2], rmn[3]));
            ws[OFF_BMAX + s] = fmaxf(fmaxf(rmx[0], rmx[1]), fmaxf(rmx[2], rmx[3]));
        }
    }
}

// ---------------- K3: full MLP table build, 2 entries per block -----------
// TBL/2 blocks x 256 thr. All intermediates in LDS; no global round-trip.
__global__ void __launch_bounds__(256) k3(
        const float* __restrict__ W1, const float* __restrict__ b1,
        const float* __restrict__ W2, const float* __restrict__ b2,
        const float* __restrict__ W3, const float* __restrict__ b3,
        float* __restrict__ ws, int nsb, float* __restrict__ tab)
{
    __shared__ float h1s[2][512];    // 4KB
    __shared__ float h2s[2][256];    // 2KB
    __shared__ float sm[2][128];     // 1KB
    __shared__ float rmn[4], rmx[4];
    const int t = threadIdx.x;

    // global min/max from per-block results
    float mn = INFINITY, mx = -INFINITY;
    for (int i = t; i < nsb; i += 256) {
        mn = fminf(mn, ws[OFF_BMIN + i]);
        mx = fmaxf(mx, ws[OFF_BMAX + i]);
    }
    #pragma unroll
    for (int m = 32; m >= 1; m >>= 1) {
        mn = fminf(mn, __shfl_xor(mn, m));
        mx = fmaxf(mx, __shfl_xor(mx, m));
    }
    if ((t & 63) == 0) { rmn[t >> 6] = mn; rmx[t >> 6] = mx; }
    __syncthreads();
    const float smin = fminf(fminf(rmn[0], rmn[1]), fminf(rmn[2], rmn[3]));
    const float smax = fmaxf(fmaxf(rmx[0], rmx[1]), fmaxf(rmx[2], rmx[3]));
    if (blockIdx.x == 0 && t == 0) { ws[OFF_MM] = smin; ws[OFF_MM + 1] = smax; }

    const float step = (smax - smin) / (float)(TBL - 1);
    const int e0 = blockIdx.x * 2;

    // layer 1: h1 for both entries (scalar input -> 512)
    for (int idx = t; idx < 2*512; idx += 256) {
        const int e = idx >> 9, k = idx & 511;
        const float s = smin + step * (float)(e0 + e);
        h1s[e][k] = fmaxf(0.f, __builtin_fmaf(s, W1[k], b1[k]));
    }
    __syncthreads();

    // layer 2: thread t = output column c, both entries; W2 per-lane row stream
    {
        const int c = t;
        const float bb = b2[c];
        float a0 = bb, a1 = bb, a0b = 0.f, a1b = 0.f;
        const float4* w2r = (const float4*)(W2 + c*512);
        #pragma unroll 8
        for (int kq = 0; kq < 128; kq += 2) {
            const float4 w2a = w2r[kq];
            const float4 hA0 = *(const float4*)(&h1s[0][kq*4]);
            const float4 hB0 = *(const float4*)(&h1s[1][kq*4]);
            a0 = __builtin_fmaf(w2a.x, hA0.x, a0);
            a0 = __builtin_fmaf(w2a.y, hA0.y, a0);
            a0 = __builtin_fmaf(w2a.z, hA0.z, a0);
            a0 = __builtin_fmaf(w2a.w, hA0.w, a0);
            a1 = __builtin_fmaf(w2a.x, hB0.x, a1);
            a1 = __builtin_fmaf(w2a.y, hB0.y, a1);
            a1 = __builtin_fmaf(w2a.z, hB0.z, a1);
            a1 = __builtin_fmaf(w2a.w, hB0.w, a1);
            const float4 w2b = w2r[kq + 1];
            const float4 hA1 = *(const float4*)(&h1s[0][kq*4 + 4]);
            const float4 hB1 = *(const float4*)(&h1s[1][kq*4 + 4]);
            a0b = __builtin_fmaf(w2b.x, hA1.x, a0b);
            a0b = __builtin_fmaf(w2b.y, hA1.y, a0b);
            a0b = __builtin_fmaf(w2b.z, hA1.z, a0b);
            a0b = __builtin_fmaf(w2b.w, hA1.w, a0b);
            a1b = __builtin_fmaf(w2b.x, hB1.x, a1b);
            a1b = __builtin_fmaf(w2b.y, hB1.y, a1b);
            a1b = __builtin_fmaf(w2b.z, hB1.z, a1b);
            a1b = __builtin_fmaf(w2b.w, hB1.w, a1b);
        }
        h2s[0][c] = fmaxf(0.f, a0 + a0b);
        h2s[1][c] = fmaxf(0.f, a1 + a1b);
    }
    __syncthreads();

    // layer 3: j = t&127, kh = t>>7 (k-split halves)
    {
        const int j = t & 127, kh = t >> 7;
        float acc0 = 0.f, acc1 = 0.f;
        const float4* w3r = (const float4*)(W3 + j*256 + kh*128);
        #pragma unroll 8
        for (int kq = 0; kq < 32; ++kq) {
            const float4 w3 = w3r[kq];
            const float4 hA = *(const float4*)(&h2s[0][kh*128 + kq*4]);
            const float4 hB = *(const float4*)(&h2s[1][kh*128 + kq*4]);
            acc0 = __builtin_fmaf(w3.x, hA.x, acc0);
            acc0 = __builtin_fmaf(w3.y, hA.y, acc0);
            acc0 = __builtin_fmaf(w3.z, hA.z, acc0);
            acc0 = __builtin_fmaf(w3.w, hA.w, acc0);
            acc1 = __builtin_fmaf(w3.x, hB.x, acc1);
            acc1 = __builtin_fmaf(w3.y, hB.y, acc1);
            acc1 = __builtin_fmaf(w3.z, hB.z, acc1);
            acc1 = __builtin_fmaf(w3.w, hB.w, acc1);
        }
        if (kh == 0) {
            const float bb = b3[j];
            sm[0][j] = acc0 + bb;
            sm[1][j] = acc1 + bb;
        }
        __syncthreads();
        if (kh == 1) {
            sm[0][j] = fmaxf(0.f, sm[0][j] + acc0);
            sm[1][j] = fmaxf(0.f, sm[1][j] + acc1);
        }
        __syncthreads();
    }

    // softmax per entry + pair-table write (waves 0,1 handle entries 0,1)
    const int w = t >> 6, lane = t & 63;
    if (w < 2) {
        const float v0 = sm[w][lane];
        const float v1 = sm[w][lane + 64];
        float m = fmaxf(v0, v1);
        #pragma unroll
        for (int msk = 1; msk < 64; msk <<= 1) m = fmaxf(m, __shfl_xor(m, msk));
        float p = __expf(v0 - m) + __expf(v1 - m);
        #pragma unroll
        for (int msk = 1; msk < 64; msk <<= 1) p += __shfl_xor(p, msk);
        const float inv = 1.f / p;
        const int row = e0 + w;
        const float g0 = __expf(v0 - m) * inv;
        const float g1 = __expf(v1 - m) * inv;
        if (row < TBL - 1) {
            tab[2*(row*128 + lane) + 0]      = g0;
            tab[2*(row*128 + lane + 64) + 0] = g1;
        }
        if (row >= 1) {
            tab[2*((row-1)*128 + lane) + 1]      = g0;
            tab[2*((row-1)*128 + lane + 64) + 1] = g1;
        }
    }
}

// ---------------- K4: weighted sum + (last block) critic head -------------
__global__ void __launch_bounds__(256) k4_main(
        const float* __restrict__ X,
        const float* __restrict__ scores,
        const float2* __restrict__ tab,    // pair table
        const int* __restrict__ selfp,
        float* ws,                          // Mt/c2/mm/emb/wgt/cnt live here
        const float* __restrict__ Wo1, const float* __restrict__ bo1,
        const float* __restrict__ Wo2, const float* __restrict__ bo2,
        float* __restrict__ out,
        int N, int APW, int nblk)
{
    const int t = threadIdx.x;
    const int lane = t & 63;
    const int wid = __builtin_amdgcn_readfirstlane(blockIdx.x*4 + (t >> 6));
    const int j0 = lane, j1 = lane + 64;
    const int a0 = wid * APW;
    const int a1 = min(N, a0 + APW);
    const float* __restrict__ Mt = ws + OFF_MT;
    float* wgt = ws + OFF_WGT;

    float4 M0[16], M1[16];
    #pragma unroll
    for (int q = 0; q < 16; ++q) {   // coalesced dword loads from Mt
        M0[q] = make_float4(Mt[(4*q+0)*128 + j0], Mt[(4*q+1)*128 + j0],
                            Mt[(4*q+2)*128 + j0], Mt[(4*q+3)*128 + j0]);
        M1[q] = make_float4(Mt[(4*q+0)*128 + j1], Mt[(4*q+1)*128 + j1],
                            Mt[(4*q+2)*128 + j1], Mt[(4*q+3)*128 + j1]);
    }
    const float cc0 = ws[OFF_C2 + j0], cc1 = ws[OFF_C2 + j1];
    const float smin = ws[OFF_MM], smax = ws[OFF_MM + 1];
    const float inv_step = (smax > smin) ? (float)(TBL - 1) / (smax - smin) : 0.f;
    const int self = *selfp;

    float rho0 = 0.f, rho1 = 0.f;
    if (a0 < a1) {
        float fc; float2 t0c, t1c;
        {   // prologue: table pair for first agent
            const float s = scores[a0];
            const float fi = (s - smin) * inv_step;
            int ii = (int)fi; ii = max(0, min(TBL - 2, ii));
            fc = fi - (float)ii;
            t0c = tab[ii*128 + j0]; t1c = tab[ii*128 + j1];
        }
        for (int n = a0; n < a1; ++n) {
            float fn = 0.f; float2 t0n = t0c, t1n = t1c;
            if (n + 1 < a1) {   // 1-deep pipeline on score+table loads
                const float s = scores[n + 1];
                const float fi = (s - smin) * inv_step;
                int ii = (int)fi; ii = max(0, min(TBL - 2, ii));
                fn = fi - (float)ii;
                t0n = tab[ii*128 + j0]; t1n = tab[ii*128 + j1];
            }
            const float w0 = t0c.x + fc * (t0c.y - t0c.x);
            const float w1 = t1c.x + fc * (t1c.y - t1c.x);
            const float4* xr = (const float4*)(X + ((size_t)n << 6));  // uniform -> s_load
            float a00=0.f,a01=0.f,a02=0.f,a03=0.f;
            float b00=0.f,b01=0.f,b02=0.f,b03=0.f;
            #pragma unroll
            for (int q = 0; q < 16; ++q) {
                const float4 xv = xr[q];
                a00 = __builtin_fmaf(M0[q].x, xv.x, a00);
                a01 = __builtin_fmaf(M0[q].y, xv.y, a01);
                a02 = __builtin_fmaf(M0[q].z, xv.z, a02);
                a03 = __builtin_fmaf(M0[q].w, xv.w, a03);
                b00 = __builtin_fmaf(M1[q].x, xv.x, b00);
                b01 = __builtin_fmaf(M1[q].y, xv.y, b01);
                b02 = __builtin_fmaf(M1[q].z, xv.z, b02);
                b03 = __builtin_fmaf(M1[q].w, xv.w, b03);
            }
            const float v0 = (a00 + a01) + (a02 + a03) + cc0;
            const float v1 = (b00 + b01) + (b02 + b03) + cc1;
            if (n != self) {
                rho0 = __builtin_fmaf(w0, v0, rho0);
                rho1 = __builtin_fmaf(w1, v1, rho1);
            }
            fc = fn; t0c = t0n; t1c = t1n;
        }
    }
    const int cpy = wid & 31;
    atomicAdd(&wgt[cpy*128 + j0], rho0);
    atomicAdd(&wgt[cpy*128 + j1], rho1);

    // ---- last-block-done: run the critic head ----
    __shared__ bool isLast;
    __syncthreads();                 // drain this block's atomics
    if (t == 0) {
        __threadfence();
        const unsigned v = __hip_atomic_fetch_add((unsigned*)(ws + OFF_CNT), 1u,
                              __ATOMIC_ACQ_REL, __HIP_MEMORY_SCOPE_AGENT);
        isLast = (v == (unsigned)(nblk - 1));
    }
    __syncthreads();
    if (isLast) {
        __shared__ float es[128], wg[128], red[128];
        if (t < 128) {
            es[t] = ws[OFF_EMB + t];
            float ssum = 0.f;
            for (int c = 0; c < 32; ++c)
                ssum += __hip_atomic_load(&wgt[c*128 + t], __ATOMIC_RELAXED,
                                          __HIP_MEMORY_SCOPE_AGENT);
            wg[t] = ssum;
        }
        __syncthreads();
        if (t < 128) {
            const float4* wA = (const float4*)(Wo1 + t*256);
            float ax = 0.f, ay = 0.f, az = 0.f, aw = 0.f;
            #pragma unroll 8
            for (int i = 0; i < 32; ++i) {
                const float4 wv = wA[i];
                const float4 ev = ((const float4*)es)[i];
                ax = __builtin_fmaf(wv.x, ev.x, ax);
                ay = __builtin_fmaf(wv.y, ev.y, ay);
                az = __builtin_fmaf(wv.z, ev.z, az);
                aw = __builtin_fmaf(wv.w, ev.w, aw);
            }
            #pragma unroll 8
            for (int i = 0; i < 32; ++i) {
                const float4 wv = wA[32 + i];
                const float4 gv = ((const float4*)wg)[i];
                ax = __builtin_fmaf(wv.x, gv.x, ax);
                ay = __builtin_fmaf(wv.y, gv.y, ay);
                az = __builtin_fmaf(wv.z, gv.z, az);
                aw = __builtin_fmaf(wv.w, gv.w, aw);
            }
            const float acc = ((ax + ay) + (az + aw)) + bo1[t];
            red[t] = fmaxf(acc, 0.f) * Wo2[t];
        }
        __syncthreads();
        for (int m = 64; m >= 1; m >>= 1) {
            if (t < m) red[t] += red[t + m];
            __syncthreads();
        }
        if (t == 0) out[0] = red[0] + bo2[0];
    }
}

extern "C" void kernel_launch(void* const* d_in, const int* in_sizes, int n_in,
                              void* d_out, int out_size, void* d_ws, size_t ws_size,
                              hipStream_t stream)
{
    const float* X   = (const float*)d_in[0];
    const float* We  = (const float*)d_in[1];
    const float* be  = (const float*)d_in[2];
    const float* Wv  = (const float*)d_in[3];
    const float* Wq  = (const float*)d_in[4];
    const float* bq  = (const float*)d_in[5];
    const float* Wk  = (const float*)d_in[6];
    const float* bk  = (const float*)d_in[7];
    const float* W1  = (const float*)d_in[8];
    const float* b1  = (const float*)d_in[9];
    const float* W2  = (const float*)d_in[10];
    const float* b2  = (const float*)d_in[11];
    const float* W3  = (const float*)d_in[12];
    const float* b3  = (const float*)d_in[13];
    const float* Wo1 = (const float*)d_in[14];
    const float* bo1 = (const float*)d_in[15];
    const float* Wo2 = (const float*)d_in[16];
    const float* bo2 = (const float*)d_in[17];
    const int* selfp = (const int*)d_in[18];
    float* ws = (float*)d_ws;
    float* out = (float*)d_out;

    const int N = in_sizes[0] / 64;
    const int offTab = OFF_SCORES + ((N + 63) & ~63);   // even -> float2-aligned
    const int APB = (N + SBLK - 1) / SBLK;
    const int nwaves = K4BLK * 4;
    const int APW = (N + nwaves - 1) / nwaves;

    k12<<<129 + SBLK, 256, 0, stream>>>(X, We, be, Wv, Wq, bq, Wk, bk, selfp, ws, N, APB);
    k3<<<TBL/2, 256, 0, stream>>>(W1, b1, W2, b2, W3, b3, ws, SBLK, ws + offTab);
    k4_main<<<K4BLK, 256, 0, stream>>>(X, ws + OFF_SCORES, (const float2*)(ws + offTab),
                                       selfp, ws, Wo1, bo1, Wo2, bo2, out, N, APW, K4BLK);
}

// Round 6
// 186.760 us; speedup vs baseline: 1.1269x; 1.1269x over previous
//
#include <hip/hip_runtime.h>
#include <math.h>

#define TBL 512
#define SBLK 512   // score blocks in k12
#define K4BLK 768  // k4 grid

// workspace layout (float offsets)
#define OFF_MM     64       // 2 floats: smin, smax (written by k3)
#define OFF_C2     128      // 128
#define OFF_EMB    256      // 128
#define OFF_MT     512      // 64*128  (M transposed: Mt[d][j])
#define OFF_WGT    8704     // 32*128 accumulator copies
#define OFF_BMIN   12800    // SBLK per-block minima
#define OFF_BMAX   13312    // SBLK per-block maxima
#define OFF_SCORES 13824    // N (padded); pair table follows at runtime offset

// ---------------- K12: prep (emb, Mt, c2, zeros) + scores + block minmax --
__global__ void __launch_bounds__(256) k12(
        const float* __restrict__ X,  const float* __restrict__ We,
        const float* __restrict__ be, const float* __restrict__ Wv,
        const float* __restrict__ Wq, const float* __restrict__ bq,
        const float* __restrict__ Wk, const float* __restrict__ bk,
        const int* __restrict__ selfp, float* __restrict__ ws,
        int N, int APB)
{
    const int b = blockIdx.x, t = threadIdx.x;
    if (b == 0) {
        // self embedding (for head) + zero accumulators
        const int self = *selfp;
        const float4* xs4 = (const float4*)(X + (size_t)self * 64);
        if (t < 128) {
            const float4* wr = (const float4*)(We + t*64);
            float ax = 0.f, ay = 0.f, az = 0.f, aw = 0.f;
            #pragma unroll
            for (int q = 0; q < 16; ++q) {
                const float4 wv = wr[q];
                const float4 xv = xs4[q];     // uniform -> s_load
                ax = __builtin_fmaf(wv.x, xv.x, ax);
                ay = __builtin_fmaf(wv.y, xv.y, ay);
                az = __builtin_fmaf(wv.z, xv.z, az);
                aw = __builtin_fmaf(wv.w, xv.w, aw);
            }
            ws[OFF_EMB + t] = ((ax + ay) + (az + aw)) + be[t];
        }
        for (int i = t; i < 32*128; i += 256) ws[OFF_WGT + i] = 0.f;
    } else if (b <= 128) {
        const int r = b - 1;   // row r of M = (Wv @ We); store transposed Mt[d][r]
        if (t < 64) {
            float acc = 0.f;
            #pragma unroll 8
            for (int e = 0; e < 128; ++e)
                acc = __builtin_fmaf(Wv[r*128 + e], We[e*64 + t], acc);
            ws[OFF_MT + t*128 + r] = acc;
        } else if (t == 64) {
            float acc = 0.f;
            for (int e = 0; e < 128; ++e)
                acc = __builtin_fmaf(Wv[r*128 + e], be[e], acc);
            ws[OFF_C2 + r] = acc;
        }
    } else {
        // ---- score block: redundantly fold v = We^T Wk^T q / sqrt(E) ----
        __shared__ float emb[128], qv[128], uu[128], vv[64];
        __shared__ float s0s;
        const int self = *selfp;
        const float4* xs4 = (const float4*)(X + (size_t)self * 64);
        if (t < 128) {
            const float4* wr = (const float4*)(We + t*64);
            float ax = 0.f, ay = 0.f, az = 0.f, aw = 0.f;
            #pragma unroll
            for (int q = 0; q < 16; ++q) {
                const float4 wv = wr[q];
                const float4 xv = xs4[q];
                ax = __builtin_fmaf(wv.x, xv.x, ax);
                ay = __builtin_fmaf(wv.y, xv.y, ay);
                az = __builtin_fmaf(wv.z, xv.z, az);
                aw = __builtin_fmaf(wv.w, xv.w, aw);
            }
            emb[t] = ((ax + ay) + (az + aw)) + be[t];
        }
        __syncthreads();
        if (t < 128) {
            const float4* wr = (const float4*)(Wq + t*128);
            float ax = 0.f, ay = 0.f, az = 0.f, aw = 0.f;
            #pragma unroll 8
            for (int q = 0; q < 32; ++q) {
                const float4 wv = wr[q];
                const float4 ev = ((const float4*)emb)[q];
                ax = __builtin_fmaf(wv.x, ev.x, ax);
                ay = __builtin_fmaf(wv.y, ev.y, ay);
                az = __builtin_fmaf(wv.z, ev.z, az);
                aw = __builtin_fmaf(wv.w, ev.w, aw);
            }
            qv[t] = ((ax + ay) + (az + aw)) + bq[t];
        }
        __syncthreads();
        if (t < 128) {
            float acc = 0.f;
            #pragma unroll 8
            for (int e = 0; e < 128; ++e)
                acc = __builtin_fmaf(Wk[e*128 + t], qv[e], acc);   // coalesced
            uu[t] = acc;
        }
        __syncthreads();
        const float rs = 0.08838834764831845f;  // 1/sqrt(128)
        if (t < 64) {
            float acc = 0.f;
            #pragma unroll 8
            for (int e = 0; e < 128; ++e)
                acc = __builtin_fmaf(We[e*64 + t], uu[e], acc);    // coalesced
            vv[t] = acc * rs;
        } else if (t == 64) {
            float acc = 0.f;
            for (int e = 0; e < 128; ++e)
                acc += be[e]*uu[e] + bk[e]*qv[e];
            s0s = acc * rs;
        }
        __syncthreads();

        // ---- scores for this block's agent slice ----
        const int s = b - 129;
        const int base = s * APB;
        const int n1 = min(N, base + APB);
        const int l16 = t & 15;
        const int slot = t >> 4;        // 16 agents per 256-thread pass
        const float4 vch = *(const float4*)(vv + l16*4);
        const float s0 = s0s;
        const float4* X4 = (const float4*)X;
        float* scores = ws + OFF_SCORES;
        float smin = INFINITY, smax = -INFINITY;
        for (int n = base + slot; n < n1; n += 16) {
            const float4 xv = X4[(size_t)n*16 + l16];
            float sc = xv.x*vch.x + xv.y*vch.y + xv.z*vch.z + xv.w*vch.w;
            sc += __shfl_xor(sc, 1);
            sc += __shfl_xor(sc, 2);
            sc += __shfl_xor(sc, 4);
            sc += __shfl_xor(sc, 8);
            sc += s0;
            if (l16 == 0) scores[n] = sc;
            smin = fminf(smin, sc);
            smax = fmaxf(smax, sc);
        }
        #pragma unroll
        for (int m = 32; m >= 1; m >>= 1) {
            smin = fminf(smin, __shfl_xor(smin, m));
            smax = fmaxf(smax, __shfl_xor(smax, m));
        }
        __shared__ float rmn[4], rmx[4];
        const int wv = t >> 6;
        if ((t & 63) == 0) { rmn[wv] = smin; rmx[wv] = smax; }
        __syncthreads();
        if (t == 0) {
            ws[OFF_BMIN + s] = fminf(fminf(rmn[0], rmn[1]), fminf(rmn[2], rmn[3]));
            ws[OFF_BMAX + s] = fmaxf(fmaxf(rmx[0], rmx[1]), fmaxf(rmx[2], rmx[3]));
        }
    }
}

// ---------------- K3: full MLP table build, 2 entries per block -----------
// TBL/2 blocks x 256 thr. All intermediates in LDS; no global round-trip.
__global__ void __launch_bounds__(256) k3(
        const float* __restrict__ W1, const float* __restrict__ b1,
        const float* __restrict__ W2, const float* __restrict__ b2,
        const float* __restrict__ W3, const float* __restrict__ b3,
        float* __restrict__ ws, int nsb, float* __restrict__ tab)
{
    __shared__ float h1s[2][512];    // 4KB
    __shared__ float h2s[2][256];    // 2KB
    __shared__ float sm[2][128];     // 1KB
    __shared__ float rmn[4], rmx[4];
    const int t = threadIdx.x;

    // global min/max from per-block results
    float mn = INFINITY, mx = -INFINITY;
    for (int i = t; i < nsb; i += 256) {
        mn = fminf(mn, ws[OFF_BMIN + i]);
        mx = fmaxf(mx, ws[OFF_BMAX + i]);
    }
    #pragma unroll
    for (int m = 32; m >= 1; m >>= 1) {
        mn = fminf(mn, __shfl_xor(mn, m));
        mx = fmaxf(mx, __shfl_xor(mx, m));
    }
    if ((t & 63) == 0) { rmn[t >> 6] = mn; rmx[t >> 6] = mx; }
    __syncthreads();
    const float smin = fminf(fminf(rmn[0], rmn[1]), fminf(rmn[2], rmn[3]));
    const float smax = fmaxf(fmaxf(rmx[0], rmx[1]), fmaxf(rmx[2], rmx[3]));
    if (blockIdx.x == 0 && t == 0) { ws[OFF_MM] = smin; ws[OFF_MM + 1] = smax; }

    const float step = (smax - smin) / (float)(TBL - 1);
    const int e0 = blockIdx.x * 2;

    // layer 1: h1 for both entries (scalar input -> 512)
    for (int idx = t; idx < 2*512; idx += 256) {
        const int e = idx >> 9, k = idx & 511;
        const float s = smin + step * (float)(e0 + e);
        h1s[e][k] = fmaxf(0.f, __builtin_fmaf(s, W1[k], b1[k]));
    }
    __syncthreads();

    // layer 2: thread t = output column c, both entries; W2 per-lane row stream
    {
        const int c = t;
        const float bb = b2[c];
        float a0 = bb, a1 = bb, a0b = 0.f, a1b = 0.f;
        const float4* w2r = (const float4*)(W2 + c*512);
        #pragma unroll 8
        for (int kq = 0; kq < 128; kq += 2) {
            const float4 w2a = w2r[kq];
            const float4 hA0 = *(const float4*)(&h1s[0][kq*4]);
            const float4 hB0 = *(const float4*)(&h1s[1][kq*4]);
            a0 = __builtin_fmaf(w2a.x, hA0.x, a0);
            a0 = __builtin_fmaf(w2a.y, hA0.y, a0);
            a0 = __builtin_fmaf(w2a.z, hA0.z, a0);
            a0 = __builtin_fmaf(w2a.w, hA0.w, a0);
            a1 = __builtin_fmaf(w2a.x, hB0.x, a1);
            a1 = __builtin_fmaf(w2a.y, hB0.y, a1);
            a1 = __builtin_fmaf(w2a.z, hB0.z, a1);
            a1 = __builtin_fmaf(w2a.w, hB0.w, a1);
            const float4 w2b = w2r[kq + 1];
            const float4 hA1 = *(const float4*)(&h1s[0][kq*4 + 4]);
            const float4 hB1 = *(const float4*)(&h1s[1][kq*4 + 4]);
            a0b = __builtin_fmaf(w2b.x, hA1.x, a0b);
            a0b = __builtin_fmaf(w2b.y, hA1.y, a0b);
            a0b = __builtin_fmaf(w2b.z, hA1.z, a0b);
            a0b = __builtin_fmaf(w2b.w, hA1.w, a0b);
            a1b = __builtin_fmaf(w2b.x, hB1.x, a1b);
            a1b = __builtin_fmaf(w2b.y, hB1.y, a1b);
            a1b = __builtin_fmaf(w2b.z, hB1.z, a1b);
            a1b = __builtin_fmaf(w2b.w, hB1.w, a1b);
        }
        h2s[0][c] = fmaxf(0.f, a0 + a0b);
        h2s[1][c] = fmaxf(0.f, a1 + a1b);
    }
    __syncthreads();

    // layer 3: j = t&127, kh = t>>7 (k-split halves)
    {
        const int j = t & 127, kh = t >> 7;
        float acc0 = 0.f, acc1 = 0.f;
        const float4* w3r = (const float4*)(W3 + j*256 + kh*128);
        #pragma unroll 8
        for (int kq = 0; kq < 32; ++kq) {
            const float4 w3 = w3r[kq];
            const float4 hA = *(const float4*)(&h2s[0][kh*128 + kq*4]);
            const float4 hB = *(const float4*)(&h2s[1][kh*128 + kq*4]);
            acc0 = __builtin_fmaf(w3.x, hA.x, acc0);
            acc0 = __builtin_fmaf(w3.y, hA.y, acc0);
            acc0 = __builtin_fmaf(w3.z, hA.z, acc0);
            acc0 = __builtin_fmaf(w3.w, hA.w, acc0);
            acc1 = __builtin_fmaf(w3.x, hB.x, acc1);
            acc1 = __builtin_fmaf(w3.y, hB.y, acc1);
            acc1 = __builtin_fmaf(w3.z, hB.z, acc1);
            acc1 = __builtin_fmaf(w3.w, hB.w, acc1);
        }
        if (kh == 0) {
            const float bb = b3[j];
            sm[0][j] = acc0 + bb;
            sm[1][j] = acc1 + bb;
        }
        __syncthreads();
        if (kh == 1) {
            sm[0][j] = fmaxf(0.f, sm[0][j] + acc0);
            sm[1][j] = fmaxf(0.f, sm[1][j] + acc1);
        }
        __syncthreads();
    }

    // softmax per entry + pair-table write (waves 0,1 handle entries 0,1)
    const int w = t >> 6, lane = t & 63;
    if (w < 2) {
        const float v0 = sm[w][lane];
        const float v1 = sm[w][lane + 64];
        float m = fmaxf(v0, v1);
        #pragma unroll
        for (int msk = 1; msk < 64; msk <<= 1) m = fmaxf(m, __shfl_xor(m, msk));
        float p = __expf(v0 - m) + __expf(v1 - m);
        #pragma unroll
        for (int msk = 1; msk < 64; msk <<= 1) p += __shfl_xor(p, msk);
        const float inv = 1.f / p;
        const int row = e0 + w;
        const float g0 = __expf(v0 - m) * inv;
        const float g1 = __expf(v1 - m) * inv;
        if (row < TBL - 1) {
            tab[2*(row*128 + lane) + 0]      = g0;
            tab[2*(row*128 + lane + 64) + 0] = g1;
        }
        if (row >= 1) {
            tab[2*((row-1)*128 + lane) + 1]      = g0;
            tab[2*((row-1)*128 + lane + 64) + 1] = g1;
        }
    }
}

// ---------------- K4: weighted_j = sum_n w_j(s_n) * (M[j]·x_n + c2_j) -----
// EXACT round-4 form: all-restrict scalar args, no head, no extra LDS.
__global__ void __launch_bounds__(256) k4_main(
        const float* __restrict__ X,
        const float* __restrict__ Mt,      // [64][128]
        const float* __restrict__ c2,      // [128]
        const float* __restrict__ mm,      // {smin, smax}
        const float* __restrict__ scores,
        const float2* __restrict__ tab,    // pair table
        const int* __restrict__ selfp,
        float* __restrict__ wgt,
        int N, int APW)
{
    const int lane = threadIdx.x & 63;
    const int wid = __builtin_amdgcn_readfirstlane(blockIdx.x*4 + (threadIdx.x >> 6));
    const int j0 = lane, j1 = lane + 64;
    const int a0 = wid * APW;
    const int a1 = min(N, a0 + APW);

    float4 M0[16], M1[16];
    #pragma unroll
    for (int q = 0; q < 16; ++q) {   // coalesced dword loads from Mt
        M0[q] = make_float4(Mt[(4*q+0)*128 + j0], Mt[(4*q+1)*128 + j0],
                            Mt[(4*q+2)*128 + j0], Mt[(4*q+3)*128 + j0]);
        M1[q] = make_float4(Mt[(4*q+0)*128 + j1], Mt[(4*q+1)*128 + j1],
                            Mt[(4*q+2)*128 + j1], Mt[(4*q+3)*128 + j1]);
    }
    const float cc0 = c2[j0], cc1 = c2[j1];
    const float smin = mm[0], smax = mm[1];
    const float inv_step = (smax > smin) ? (float)(TBL - 1) / (smax - smin) : 0.f;
    const int self = *selfp;

    float rho0 = 0.f, rho1 = 0.f;
    if (a0 < a1) {
        float fc; float2 t0c, t1c;
        {   // prologue: table pair for first agent
            const float s = scores[a0];
            const float fi = (s - smin) * inv_step;
            int ii = (int)fi; ii = max(0, min(TBL - 2, ii));
            fc = fi - (float)ii;
            t0c = tab[ii*128 + j0]; t1c = tab[ii*128 + j1];
        }
        for (int n = a0; n < a1; ++n) {
            float fn = 0.f; float2 t0n = t0c, t1n = t1c;
            if (n + 1 < a1) {   // 1-deep pipeline on score+table loads
                const float s = scores[n + 1];
                const float fi = (s - smin) * inv_step;
                int ii = (int)fi; ii = max(0, min(TBL - 2, ii));
                fn = fi - (float)ii;
                t0n = tab[ii*128 + j0]; t1n = tab[ii*128 + j1];
            }
            const float w0 = t0c.x + fc * (t0c.y - t0c.x);
            const float w1 = t1c.x + fc * (t1c.y - t1c.x);
            const float4* xr = (const float4*)(X + ((size_t)n << 6));  // uniform -> s_load
            float a00=0.f,a01=0.f,a02=0.f,a03=0.f;
            float b00=0.f,b01=0.f,b02=0.f,b03=0.f;
            #pragma unroll
            for (int q = 0; q < 16; ++q) {
                const float4 xv = xr[q];
                a00 = __builtin_fmaf(M0[q].x, xv.x, a00);
                a01 = __builtin_fmaf(M0[q].y, xv.y, a01);
                a02 = __builtin_fmaf(M0[q].z, xv.z, a02);
                a03 = __builtin_fmaf(M0[q].w, xv.w, a03);
                b00 = __builtin_fmaf(M1[q].x, xv.x, b00);
                b01 = __builtin_fmaf(M1[q].y, xv.y, b01);
                b02 = __builtin_fmaf(M1[q].z, xv.z, b02);
                b03 = __builtin_fmaf(M1[q].w, xv.w, b03);
            }
            const float v0 = (a00 + a01) + (a02 + a03) + cc0;
            const float v1 = (b00 + b01) + (b02 + b03) + cc1;
            if (n != self) {
                rho0 = __builtin_fmaf(w0, v0, rho0);
                rho1 = __builtin_fmaf(w1, v1, rho1);
            }
            fc = fn; t0c = t0n; t1c = t1n;
        }
    }
    const int cpy = wid & 31;
    atomicAdd(&wgt[cpy*128 + j0], rho0);
    atomicAdd(&wgt[cpy*128 + j1], rho1);
}

// ---------------- K5: critic head ----------------------------------------
__global__ void __launch_bounds__(128) k5_final(
        const float* __restrict__ Wo1, const float* __restrict__ bo1,
        const float* __restrict__ Wo2, const float* __restrict__ bo2,
        float* ws, float* out)
{
    __shared__ float es[128], wg[128], red[128];
    const int t = threadIdx.x;
    es[t] = ws[OFF_EMB + t];
    float s = 0.f;
    for (int c = 0; c < 32; ++c) s += ws[OFF_WGT + c*128 + t];
    wg[t] = s;
    __syncthreads();
    const float4* wA = (const float4*)(Wo1 + t*256);
    float ax = 0.f, ay = 0.f, az = 0.f, aw = 0.f;
    #pragma unroll 8
    for (int i = 0; i < 32; ++i) {
        const float4 wv = wA[i];
        const float4 ev = ((const float4*)es)[i];
        ax = __builtin_fmaf(wv.x, ev.x, ax);
        ay = __builtin_fmaf(wv.y, ev.y, ay);
        az = __builtin_fmaf(wv.z, ev.z, az);
        aw = __builtin_fmaf(wv.w, ev.w, aw);
    }
    #pragma unroll 8
    for (int i = 0; i < 32; ++i) {
        const float4 wv = wA[32 + i];
        const float4 gv = ((const float4*)wg)[i];
        ax = __builtin_fmaf(wv.x, gv.x, ax);
        ay = __builtin_fmaf(wv.y, gv.y, ay);
        az = __builtin_fmaf(wv.z, gv.z, az);
        aw = __builtin_fmaf(wv.w, gv.w, aw);
    }
    const float acc = ((ax + ay) + (az + aw)) + bo1[t];
    red[t] = fmaxf(acc, 0.f) * Wo2[t];
    __syncthreads();
    for (int m = 64; m >= 1; m >>= 1) {
        if (t < m) red[t] += red[t + m];
        __syncthreads();
    }
    if (t == 0) out[0] = red[0] + bo2[0];
}

extern "C" void kernel_launch(void* const* d_in, const int* in_sizes, int n_in,
                              void* d_out, int out_size, void* d_ws, size_t ws_size,
                              hipStream_t stream)
{
    const float* X   = (const float*)d_in[0];
    const float* We  = (const float*)d_in[1];
    const float* be  = (const float*)d_in[2];
    const float* Wv  = (const float*)d_in[3];
    const float* Wq  = (const float*)d_in[4];
    const float* bq  = (const float*)d_in[5];
    const float* Wk  = (const float*)d_in[6];
    const float* bk  = (const float*)d_in[7];
    const float* W1  = (const float*)d_in[8];
    const float* b1  = (const float*)d_in[9];
    const float* W2  = (const float*)d_in[10];
    const float* b2  = (const float*)d_in[11];
    const float* W3  = (const float*)d_in[12];
    const float* b3  = (const float*)d_in[13];
    const float* Wo1 = (const float*)d_in[14];
    const float* bo1 = (const float*)d_in[15];
    const float* Wo2 = (const float*)d_in[16];
    const float* bo2 = (const float*)d_in[17];
    const int* selfp = (const int*)d_in[18];
    float* ws = (float*)d_ws;
    float* out = (float*)d_out;

    const int N = in_sizes[0] / 64;
    const int offTab = OFF_SCORES + ((N + 63) & ~63);   // even -> float2-aligned
    const int APB = (N + SBLK - 1) / SBLK;
    const int nwaves = K4BLK * 4;
    const int APW = (N + nwaves - 1) / nwaves;

    k12<<<129 + SBLK, 256, 0, stream>>>(X, We, be, Wv, Wq, bq, Wk, bk, selfp, ws, N, APB);
    k3<<<TBL/2, 256, 0, stream>>>(W1, b1, W2, b2, W3, b3, ws, SBLK, ws + offTab);
    k4_main<<<K4BLK, 256, 0, stream>>>(X, ws + OFF_MT, ws + OFF_C2, ws + OFF_MM,
                                       ws + OFF_SCORES, (const float2*)(ws + offTab),
                                       selfp, ws + OFF_WGT, N, APW);
    k5_final<<<1, 128, 0, stream>>>(Wo1, bo1, Wo2, bo2, ws, out);
}